// Round 1
// baseline (581.993 us; speedup 1.0000x reference)
//
#include <hip/hip_runtime.h>

// SRNet: per-pixel MLP 4 -> 64 -> 64 x4 -> 16 with 3x3 softmax sampler and
// 4x pixel shuffle. B=16, H=W=256, Hp=Wp=254, OW=1016.
//
// Round 0: fp32 VALU version, one thread per (b, hp, wp) pixel. All layer
// loops fully unrolled so activations stay in VGPRs; weights read via
// uniform (scalar) loads from global.

#define HIDN 64

__device__ __forceinline__ void layer64(float (&x)[HIDN],
                                        const float* __restrict__ w,
                                        const float* __restrict__ bb)
{
    float r[HIDN];
#pragma unroll
    for (int i = 0; i < HIDN; ++i) r[i] = fmaxf(x[i], 0.0f);
#pragma unroll
    for (int o = 0; o < HIDN; ++o) {
        float acc = bb[o];
#pragma unroll
        for (int i = 0; i < HIDN; ++i) acc = fmaf(r[i], w[o * HIDN + i], acc);
        x[o] = acc;
    }
}

__global__ __launch_bounds__(256, 1) void srnet_fwd(
    const float* __restrict__ x_in,
    const float* __restrict__ sampler_w,
    const float* __restrict__ w1, const float* __restrict__ b1,
    const float* __restrict__ w2, const float* __restrict__ b2,
    const float* __restrict__ w3, const float* __restrict__ b3,
    const float* __restrict__ w4, const float* __restrict__ b4,
    const float* __restrict__ w5, const float* __restrict__ b5,
    const float* __restrict__ w6, const float* __restrict__ b6,
    float* __restrict__ out)
{
    constexpr int W = 256, Hp = 254, Wp = 254, OW = 1016;
    const int wp = threadIdx.x;
    const int hp = blockIdx.x % Hp;
    const int b  = blockIdx.x / Hp;
    if (wp >= Wp) return;

    // --- softmax over sampler_w rows (4 x 9), uniform across threads ---
    float ws[4][9];
#pragma unroll
    for (int c = 0; c < 4; ++c) {
        float m = -1e30f;
#pragma unroll
        for (int k = 0; k < 9; ++k) m = fmaxf(m, sampler_w[c * 9 + k]);
        float e[9];
        float sum = 0.0f;
#pragma unroll
        for (int k = 0; k < 9; ++k) {
            e[k] = __expf(sampler_w[c * 9 + k] - m);
            sum += e[k];
        }
        const float inv = 1.0f / sum;
#pragma unroll
        for (int k = 0; k < 9; ++k) ws[c][k] = e[k] * inv;
    }

    // --- 3x3 patch ---
    const float* img = x_in + (size_t)b * (W * W);
    float p[9];
#pragma unroll
    for (int i = 0; i < 3; ++i)
#pragma unroll
        for (int j = 0; j < 3; ++j)
            p[i * 3 + j] = img[(hp + i) * W + (wp + j)];

    // --- sampler: s[c] = sum_k p[k] * ws[c][k] ---
    float s[4];
#pragma unroll
    for (int c = 0; c < 4; ++c) {
        float acc = 0.0f;
#pragma unroll
        for (int k = 0; k < 9; ++k) acc = fmaf(p[k], ws[c][k], acc);
        s[c] = acc;
    }

    // --- layer 1: 4 -> 64 (no relu on input) ---
    float x[HIDN];
#pragma unroll
    for (int o = 0; o < HIDN; ++o) {
        const float* wr = w1 + o * 4;
        x[o] = b1[o];
        x[o] = fmaf(s[0], wr[0], x[o]);
        x[o] = fmaf(s[1], wr[1], x[o]);
        x[o] = fmaf(s[2], wr[2], x[o]);
        x[o] = fmaf(s[3], wr[3], x[o]);
    }

    // --- hidden layers 2..5: relu + 64 -> 64 ---
    layer64(x, w2, b2);
    layer64(x, w3, b3);
    layer64(x, w4, b4);
    layer64(x, w5, b5);

    // --- output layer: relu + 64 -> 16 ---
    float r[HIDN];
#pragma unroll
    for (int i = 0; i < HIDN; ++i) r[i] = fmaxf(x[i], 0.0f);
    float y[16];
#pragma unroll
    for (int u = 0; u < 16; ++u) {
        float acc = b6[u];
#pragma unroll
        for (int i = 0; i < HIDN; ++i) acc = fmaf(r[i], w6[u * HIDN + i], acc);
        y[u] = acc;
    }

    // --- pixel shuffle store: out[b][hp*4+u1][wp*4+u2] = y[u1*4+u2] ---
    float* ob = out + (size_t)b * OW * OW + (size_t)(hp * 4) * OW + wp * 4;
#pragma unroll
    for (int u1 = 0; u1 < 4; ++u1) {
        float4 v = make_float4(y[u1 * 4 + 0], y[u1 * 4 + 1],
                               y[u1 * 4 + 2], y[u1 * 4 + 3]);
        *reinterpret_cast<float4*>(ob + (size_t)u1 * OW) = v;
    }
}

extern "C" void kernel_launch(void* const* d_in, const int* in_sizes, int n_in,
                              void* d_out, int out_size, void* d_ws, size_t ws_size,
                              hipStream_t stream)
{
    const float* x_in      = (const float*)d_in[0];
    const float* sampler_w = (const float*)d_in[1];
    // d_in[2] = sampler_b, multiplied by 0.0 in the reference -> unused
    const float* w1 = (const float*)d_in[3];
    const float* b1 = (const float*)d_in[4];
    const float* w2 = (const float*)d_in[5];
    const float* b2 = (const float*)d_in[6];
    const float* w3 = (const float*)d_in[7];
    const float* b3 = (const float*)d_in[8];
    const float* w4 = (const float*)d_in[9];
    const float* b4 = (const float*)d_in[10];
    const float* w5 = (const float*)d_in[11];
    const float* b5 = (const float*)d_in[12];
    const float* w6 = (const float*)d_in[13];
    const float* b6 = (const float*)d_in[14];
    float* out = (float*)d_out;

    dim3 grid(16 * 254);
    dim3 block(256);
    hipLaunchKernelGGL(srnet_fwd, grid, block, 0, stream,
                       x_in, sampler_w, w1, b1, w2, b2, w3, b3,
                       w4, b4, w5, b5, w6, b6, out);
}

// Round 2
// 95.501 us; speedup vs baseline: 6.0941x; 6.0941x over previous
//
#include <hip/hip_runtime.h>

// SRNet via MFMA (v_mfma_f32_32x32x16_f16), D = W * X^T formulation.
// Each wave processes 32 pixels (pixel = lane&31 = matrix column m).
// Inter-layer D-layout -> B-layout relayout via 8x permlane32_swap per layer.
// Sampler (3x3 softmax conv) folded into layer-1 weights: W1eff = w1 @ softmax(sampler_w).
// Biases added from LDS (broadcast ds_read_b128, 2 distinct addrs -> conflict-free).

typedef _Float16 f16x8  __attribute__((ext_vector_type(8)));
typedef _Float16 half2v __attribute__((ext_vector_type(2)));
typedef float    f32x16 __attribute__((ext_vector_type(16)));
typedef unsigned int u32;

union FragU { f16x8 v; u32 w[4]; };

__device__ __forceinline__ u32 pkrne(float a, float b) {
    half2v h; h.x = (_Float16)a; h.y = (_Float16)b;
    return __builtin_bit_cast(u32, h);
}

__device__ __forceinline__ f32x16 mfma16(const FragU& a, const FragU& b, f32x16 c) {
    return __builtin_amdgcn_mfma_f32_32x32x16_f16(a.v, b.v, c, 0, 0, 0);
}

// permlane32_swap: ret0[l] = l<32 ? a[l] : b[l-32];  ret1[l] = l<32 ? a[l+32] : b[l]
__device__ __forceinline__ void pl32(u32& x, u32& y) {
    auto r = __builtin_amdgcn_permlane32_swap((int)x, (int)y, false, false);
    x = (u32)r[0]; y = (u32)r[1];
}

__device__ __forceinline__ void calc_coords(int g, int m, int& b, int& hp, int& wp) {
    unsigned P = (unsigned)(g * 32 + m);
    unsigned bb = P / 64516u;            // 254*254
    unsigned rem = P - bb * 64516u;
    unsigned h = rem / 254u;
    b = (int)bb; hp = (int)h; wp = (int)(rem - h * 254u);
}

__device__ __forceinline__ void load_patches(const float* __restrict__ x_in,
                                             int b, int hp, int wp, float p[9]) {
    const float* base = x_in + ((size_t)b << 16) + hp * 256 + wp;
#pragma unroll
    for (int i = 0; i < 3; ++i)
#pragma unroll
        for (int j = 0; j < 3; ++j)
            p[i * 3 + j] = base[i * 256 + j];
}

// Epilogue: acc(2 tiles, D-layout) + bias -> relu -> f16 pack -> permlane -> B frags (4 ksteps)
__device__ __forceinline__ void epilogue(const f32x16 (&acc)[2], FragU (&B)[4],
                                         const float* bias_base, int lo) {
    u32 ww[2][4][2];
#pragma unroll
    for (int mt = 0; mt < 2; ++mt) {
#pragma unroll
        for (int q = 0; q < 4; ++q) {
            const float4 b4 = *(const float4*)(bias_base + 32 * mt + 8 * q + 4 * lo);
            float x0 = fmaxf(acc[mt][4 * q + 0] + b4.x, 0.f);
            float x1 = fmaxf(acc[mt][4 * q + 1] + b4.y, 0.f);
            float x2 = fmaxf(acc[mt][4 * q + 2] + b4.z, 0.f);
            float x3 = fmaxf(acc[mt][4 * q + 3] + b4.w, 0.f);
            ww[mt][q][0] = pkrne(x0, x1);
            ww[mt][q][1] = pkrne(x2, x3);
        }
    }
#pragma unroll
    for (int ks = 0; ks < 4; ++ks) {
#pragma unroll
        for (int p = 0; p < 2; ++p) {
            u32 a = ww[ks >> 1][2 * (ks & 1) + 0][p];
            u32 b = ww[ks >> 1][2 * (ks & 1) + 1][p];
            pl32(a, b);
            B[ks].w[p]     = a;
            B[ks].w[p + 2] = b;
        }
    }
}

__global__ __launch_bounds__(256, 1) void srnet_mfma(
    const float* __restrict__ x_in,
    const float* __restrict__ sampler_w,
    const float* __restrict__ w1, const float* __restrict__ b1,
    const float* __restrict__ w2, const float* __restrict__ b2,
    const float* __restrict__ w3, const float* __restrict__ b3,
    const float* __restrict__ w4, const float* __restrict__ b4,
    const float* __restrict__ w5, const float* __restrict__ b5,
    const float* __restrict__ w6, const float* __restrict__ b6,
    float* __restrict__ out)
{
    constexpr int NG = 32258;        // (16*254*254)/32
    constexpr int OW = 1016;

    const int lane = threadIdx.x & 63;
    const int m    = lane & 31;      // pixel slot / matrix column
    const int lo   = lane >> 5;      // half-wave id

    // ---- stage biases to LDS: [0:64) b1 .. [256:320) b5, [320:336) b6 ----
    __shared__ __align__(16) float bias_lds[336];
    for (int i = threadIdx.x; i < 336; i += 256) {
        float v;
        if      (i < 64)  v = b1[i];
        else if (i < 128) v = b2[i - 64];
        else if (i < 192) v = b3[i - 128];
        else if (i < 256) v = b4[i - 192];
        else if (i < 320) v = b5[i - 256];
        else              v = b6[i - 320];
        bias_lds[i] = v;
    }
    __syncthreads();

    // ---- uniform softmax of sampler (4 x 9) ----
    float ws[4][9];
#pragma unroll
    for (int c = 0; c < 4; ++c) {
        float mx = sampler_w[c * 9];
#pragma unroll
        for (int k = 1; k < 9; ++k) mx = fmaxf(mx, sampler_w[c * 9 + k]);
        float e[9]; float sum = 0.f;
#pragma unroll
        for (int k = 0; k < 9; ++k) { e[k] = __expf(sampler_w[c * 9 + k] - mx); sum += e[k]; }
        float inv = 1.f / sum;
#pragma unroll
        for (int k = 0; k < 9; ++k) ws[c][k] = e[k] * inv;
    }

    // ---- layer-1 effective weights: W1eff[o][k] = sum_c w1[o][c] * ws[c][k], K padded to 16 ----
    // A frag: lane holds rows o=32*mt+m, k = 8*lo + j  (k=0..8 nonzero)
    FragU w1f[2];
#pragma unroll
    for (int mt = 0; mt < 2; ++mt) {
        const int row = 32 * mt + m;
        const float4 wr = *(const float4*)(w1 + row * 4);
        float we[9];
#pragma unroll
        for (int k = 0; k < 9; ++k)
            we[k] = wr.x * ws[0][k] + wr.y * ws[1][k] + wr.z * ws[2][k] + wr.w * ws[3][k];
        if (lo == 0) {
            w1f[mt].w[0] = pkrne(we[0], we[1]);
            w1f[mt].w[1] = pkrne(we[2], we[3]);
            w1f[mt].w[2] = pkrne(we[4], we[5]);
            w1f[mt].w[3] = pkrne(we[6], we[7]);
        } else {
            w1f[mt].w[0] = pkrne(we[8], 0.f);
            w1f[mt].w[1] = 0; w1f[mt].w[2] = 0; w1f[mt].w[3] = 0;
        }
    }

    // ---- hidden-layer weight frags: wf[L][mt][ks], lane holds W[32mt+m][16ks+8lo .. +7] ----
    FragU wf[4][2][4];
    const float* wptr[4] = { w2, w3, w4, w5 };
#pragma unroll
    for (int L = 0; L < 4; ++L)
#pragma unroll
        for (int mt = 0; mt < 2; ++mt)
#pragma unroll
            for (int ks = 0; ks < 4; ++ks) {
                const float* src = wptr[L] + (32 * mt + m) * 64 + 16 * ks + 8 * lo;
                const float4 f0 = *(const float4*)(src);
                const float4 f1 = *(const float4*)(src + 4);
                wf[L][mt][ks].w[0] = pkrne(f0.x, f0.y);
                wf[L][mt][ks].w[1] = pkrne(f0.z, f0.w);
                wf[L][mt][ks].w[2] = pkrne(f1.x, f1.y);
                wf[L][mt][ks].w[3] = pkrne(f1.z, f1.w);
            }

    // ---- output-layer frags (rows 16..31 zero-padded) ----
    FragU w6f[4];
    const bool vrow = (m < 16);
    const int r6 = vrow ? m : 0;
#pragma unroll
    for (int ks = 0; ks < 4; ++ks) {
        const float* src = w6 + r6 * 64 + 16 * ks + 8 * lo;
        const float4 f0 = *(const float4*)(src);
        const float4 f1 = *(const float4*)(src + 4);
        w6f[ks].w[0] = vrow ? pkrne(f0.x, f0.y) : 0;
        w6f[ks].w[1] = vrow ? pkrne(f0.z, f0.w) : 0;
        w6f[ks].w[2] = vrow ? pkrne(f1.x, f1.y) : 0;
        w6f[ks].w[3] = vrow ? pkrne(f1.z, f1.w) : 0;
    }

    // ---- grid-stride over pixel groups of 32, patch prefetch one group ahead ----
    const int wid = (int)((blockIdx.x * blockDim.x + threadIdx.x) >> 6);
    const int nw  = (int)((gridDim.x * blockDim.x) >> 6);

    int g = wid;
    float p[9];
    if (g < NG) {
        int cb, chp, cwp;
        calc_coords(g, m, cb, chp, cwp);
        load_patches(x_in, cb, chp, cwp, p);
    }

    while (g < NG) {
        const int gn = g + nw;

        // B1 frag from patches: lo=0 -> k=0..7 = p0..p7 ; lo=1 -> k=8 = p8
        FragU B1;
        if (lo == 0) {
            B1.w[0] = pkrne(p[0], p[1]);
            B1.w[1] = pkrne(p[2], p[3]);
            B1.w[2] = pkrne(p[4], p[5]);
            B1.w[3] = pkrne(p[6], p[7]);
        } else {
            B1.w[0] = pkrne(p[8], 0.f);
            B1.w[1] = 0; B1.w[2] = 0; B1.w[3] = 0;
        }

        // prefetch next group's patches (latency hidden under the 6 layers)
        float pn[9];
        if (gn < NG) {
            int nb, nhp, nwp;
            calc_coords(gn, m, nb, nhp, nwp);
            load_patches(x_in, nb, nhp, nwp, pn);
        }

        // ---- layer 1: 9(pad 16) -> 64 ----
        f32x16 acc[2];
        f32x16 z{};
        acc[0] = mfma16(w1f[0], B1, z);
        acc[1] = mfma16(w1f[1], B1, z);

        FragU B[4];
        epilogue(acc, B, bias_lds + 0, lo);          // +b1, relu, relayout

        // ---- layers 2..5: 64 -> 64 ----
#pragma unroll
        for (int L = 0; L < 4; ++L) {
            f32x16 a2[2];
            a2[0] = z; a2[1] = z;
#pragma unroll
            for (int ks = 0; ks < 4; ++ks) {
                a2[0] = mfma16(wf[L][0][ks], B[ks], a2[0]);
                a2[1] = mfma16(wf[L][1][ks], B[ks], a2[1]);
            }
            epilogue(a2, B, bias_lds + 64 * (L + 1), lo);
        }

        // ---- layer 6: 64 -> 16 (rows 16..31 are zero) ----
        f32x16 aF = z;
#pragma unroll
        for (int ks = 0; ks < 4; ++ks) aF = mfma16(w6f[ks], B[ks], aF);

        // ---- +b6 and pixel-shuffle store ----
        // lane holds y[o], o = (reg&3) + 8*(reg>>2) + 4*lo for regs 0..7
        const float4 b6a = *(const float4*)(bias_lds + 320 + 4 * lo);       // o = 0..3  +4lo
        const float4 b6b = *(const float4*)(bias_lds + 320 + 8 + 4 * lo);   // o = 8..11 +4lo
        float4 v0 = make_float4(aF[0] + b6a.x, aF[1] + b6a.y, aF[2] + b6a.z, aF[3] + b6a.w);
        float4 v1 = make_float4(aF[4] + b6b.x, aF[5] + b6b.y, aF[6] + b6b.z, aF[7] + b6b.w);

        int cb, chp, cwp;
        calc_coords(g, m, cb, chp, cwp);
        float* obase = out + (size_t)cb * (OW * OW) + (size_t)(4 * chp + lo) * OW + 4 * cwp;
        *(float4*)(obase)          = v0;   // row u1 = lo
        *(float4*)(obase + 2 * OW) = v1;   // row u1 = 2 + lo

        g = gn;
#pragma unroll
        for (int k = 0; k < 9; ++k) p[k] = pn[k];
    }
}

extern "C" void kernel_launch(void* const* d_in, const int* in_sizes, int n_in,
                              void* d_out, int out_size, void* d_ws, size_t ws_size,
                              hipStream_t stream)
{
    const float* x_in      = (const float*)d_in[0];
    const float* sampler_w = (const float*)d_in[1];
    // d_in[2] = sampler_b (unused: reference multiplies it by 0)
    const float* w1 = (const float*)d_in[3];
    const float* b1 = (const float*)d_in[4];
    const float* w2 = (const float*)d_in[5];
    const float* b2 = (const float*)d_in[6];
    const float* w3 = (const float*)d_in[7];
    const float* b3 = (const float*)d_in[8];
    const float* w4 = (const float*)d_in[9];
    const float* b4 = (const float*)d_in[10];
    const float* w5 = (const float*)d_in[11];
    const float* b5 = (const float*)d_in[12];
    const float* w6 = (const float*)d_in[13];
    const float* b6 = (const float*)d_in[14];
    float* out = (float*)d_out;

    dim3 grid(512);   // 2048 waves, grid-stride over 32258 groups
    dim3 block(256);
    hipLaunchKernelGGL(srnet_mfma, grid, block, 0, stream,
                       x_in, sampler_w, w1, b1, w2, b2, w3, b3,
                       w4, b4, w5, b5, w6, b6, out);
}

// Round 4
// 65.629 us; speedup vs baseline: 8.8679x; 1.4552x over previous
//
#include <hip/hip_runtime.h>

// SRNet via MFMA (v_mfma_f32_32x32x16_f16), D = W * X^T, 2 pixel-groups per
// wave interleaved for ILP (1 wave/SIMD by design; weights live in VGPRs).
// Epilogue: v_cvt_pkrtz + v_pk_add_f16 (packed bias from LDS) + v_pk_max_f16,
// then 8x permlane32_swap relayout D->B. b1 folded into layer-1 K-padding.

typedef _Float16 f16x8  __attribute__((ext_vector_type(8)));
typedef _Float16 half2v __attribute__((ext_vector_type(2)));
typedef float    f32x16 __attribute__((ext_vector_type(16)));
typedef unsigned int u32;
typedef u32 u32x4 __attribute__((ext_vector_type(4)));

union FragU { f16x8 v; u32 w[4]; };

__device__ __forceinline__ u32 pkrne(float a, float b) {
    half2v h; h.x = (_Float16)a; h.y = (_Float16)b;
    return __builtin_bit_cast(u32, h);
}
__device__ __forceinline__ u32 pkrtz(float a, float b) {
    return __builtin_bit_cast(u32, __builtin_amdgcn_cvt_pkrtz(a, b));
}
__device__ __forceinline__ u32 pk_add(u32 a, u32 b) {
    half2v r = __builtin_bit_cast(half2v, a) + __builtin_bit_cast(half2v, b);
    return __builtin_bit_cast(u32, r);
}
__device__ __forceinline__ u32 pk_relu(u32 a) {
    half2v z = {};
    half2v r = __builtin_elementwise_max(__builtin_bit_cast(half2v, a), z);
    return __builtin_bit_cast(u32, r);
}

__device__ __forceinline__ f32x16 mfma16(const FragU& a, const FragU& b, f32x16 c) {
    return __builtin_amdgcn_mfma_f32_32x32x16_f16(a.v, b.v, c, 0, 0, 0);
}

// permlane32_swap: ret0[l] = l<32 ? a[l] : b[l-32];  ret1[l] = l<32 ? a[l+32] : b[l]
__device__ __forceinline__ void pl32(u32& x, u32& y) {
    auto r = __builtin_amdgcn_permlane32_swap((int)x, (int)y, false, false);
    x = (u32)r[0]; y = (u32)r[1];
}

__device__ __forceinline__ void calc_coords(int g, int m, int& b, int& hp, int& wp) {
    unsigned P = (unsigned)(g * 32 + m);
    unsigned bb = P / 64516u;            // 254*254
    unsigned rem = P - bb * 64516u;
    unsigned h = rem / 254u;
    b = (int)bb; hp = (int)h; wp = (int)(rem - h * 254u);
}

__device__ __forceinline__ void load_patches(const float* __restrict__ x_in,
                                             int g, int m, float p[9]) {
    int b, hp, wp;
    calc_coords(g, m, b, hp, wp);
    const float* base = x_in + ((size_t)b << 16) + hp * 256 + wp;
#pragma unroll
    for (int i = 0; i < 3; ++i)
#pragma unroll
        for (int j = 0; j < 3; ++j)
            p[i * 3 + j] = base[i * 256 + j];
}

// acc(2 tiles, D-layout) -> [+bias] -> relu -> f16 -> permlane -> B frags
template<bool BIAS>
__device__ __forceinline__ void epilogue(const f32x16& A0, const f32x16& A1,
                                         FragU (&B)[4],
                                         const u32* __restrict__ bias_base) {
    u32 bw[16];
    if (BIAS) {
        const u32x4* bp = (const u32x4*)bias_base;   // 4x ds_read_b128, broadcast
#pragma unroll
        for (int v = 0; v < 4; ++v) {
            u32x4 t = bp[v];
            bw[4 * v + 0] = t.x; bw[4 * v + 1] = t.y;
            bw[4 * v + 2] = t.z; bw[4 * v + 3] = t.w;
        }
    }
    u32 ww[2][4][2];
    const f32x16* accs[2] = { &A0, &A1 };
#pragma unroll
    for (int mt = 0; mt < 2; ++mt) {
#pragma unroll
        for (int q = 0; q < 4; ++q) {
            u32 w0 = pkrtz((*accs[mt])[4 * q + 0], (*accs[mt])[4 * q + 1]);
            u32 w1 = pkrtz((*accs[mt])[4 * q + 2], (*accs[mt])[4 * q + 3]);
            if (BIAS) {
                w0 = pk_add(w0, bw[mt * 8 + q * 2 + 0]);
                w1 = pk_add(w1, bw[mt * 8 + q * 2 + 1]);
            }
            ww[mt][q][0] = pk_relu(w0);
            ww[mt][q][1] = pk_relu(w1);
        }
    }
#pragma unroll
    for (int ks = 0; ks < 4; ++ks) {
#pragma unroll
        for (int p = 0; p < 2; ++p) {
            u32 a = ww[ks >> 1][2 * (ks & 1) + 0][p];
            u32 b = ww[ks >> 1][2 * (ks & 1) + 1][p];
            pl32(a, b);
            B[ks].w[p]     = a;
            B[ks].w[p + 2] = b;
        }
    }
}

__device__ __forceinline__ void pack_B1(const float p[9], int lo, FragU& B1) {
    if (lo == 0) {
        B1.w[0] = pkrtz(p[0], p[1]);
        B1.w[1] = pkrtz(p[2], p[3]);
        B1.w[2] = pkrtz(p[4], p[5]);
        B1.w[3] = pkrtz(p[6], p[7]);
    } else {
        B1.w[0] = pkrtz(p[8], 1.0f);     // k=9 slot multiplies the b1 column
        B1.w[1] = 0; B1.w[2] = 0; B1.w[3] = 0;
    }
}

__global__ __launch_bounds__(256, 1) void srnet_mfma(
    const float* __restrict__ x_in,
    const float* __restrict__ sampler_w,
    const float* __restrict__ w1, const float* __restrict__ b1,
    const float* __restrict__ w2, const float* __restrict__ b2,
    const float* __restrict__ w3, const float* __restrict__ b3,
    const float* __restrict__ w4, const float* __restrict__ b4,
    const float* __restrict__ w5, const float* __restrict__ b5,
    const float* __restrict__ w6, const float* __restrict__ b6,
    float* __restrict__ out)
{
    constexpr int NG    = 32258;     // (16*254*254)/32
    constexpr int NPAIR = NG / 2;    // 16129
    constexpr int OW    = 1016;

    const int lane = threadIdx.x & 63;
    const int m    = lane & 31;
    const int lo   = lane >> 5;

    // ---- LDS: packed f16 bias pairs for layers 2..5, f32 b6 ----
    // bias_pk flat index: ((L*2+lo)*2+mt)*8 + q*2 + p
    __shared__ __align__(16) u32 bias_pk[128];
    __shared__ float b6s[16];
    {
        const int t = threadIdx.x;
        if (t < 128) {
            int L  = t >> 5, r = t & 31;
            int plo = (r >> 4) & 1, pmt = (r >> 3) & 1, pq = (r >> 1) & 3, pp = r & 1;
            const float* bsrc = (L == 0) ? b2 : (L == 1) ? b3 : (L == 2) ? b4 : b5;
            int ch = 32 * pmt + 8 * pq + 4 * plo + 2 * pp;
            bias_pk[t] = pkrne(bsrc[ch], bsrc[ch + 1]);
        }
        if (t < 16) b6s[t] = b6[t];
    }
    __syncthreads();

    float b6r[8];
#pragma unroll
    for (int j = 0; j < 4; ++j) { b6r[j] = b6s[4 * lo + j]; b6r[4 + j] = b6s[8 + 4 * lo + j]; }

    // ---- uniform softmax of sampler (4 x 9) ----
    float ws[4][9];
#pragma unroll
    for (int c = 0; c < 4; ++c) {
        float mx = sampler_w[c * 9];
#pragma unroll
        for (int k = 1; k < 9; ++k) mx = fmaxf(mx, sampler_w[c * 9 + k]);
        float e[9]; float sum = 0.f;
#pragma unroll
        for (int k = 0; k < 9; ++k) { e[k] = __expf(sampler_w[c * 9 + k] - mx); sum += e[k]; }
        float inv = 1.f / sum;
#pragma unroll
        for (int k = 0; k < 9; ++k) ws[c][k] = e[k] * inv;
    }

    // ---- layer-1 effective weights (sampler folded in), b1 in k=9 column ----
    FragU w1f[2];
#pragma unroll
    for (int mt = 0; mt < 2; ++mt) {
        const int row = 32 * mt + m;
        const float4 wr = *(const float4*)(w1 + row * 4);
        float we[9];
#pragma unroll
        for (int k = 0; k < 9; ++k)
            we[k] = wr.x * ws[0][k] + wr.y * ws[1][k] + wr.z * ws[2][k] + wr.w * ws[3][k];
        if (lo == 0) {
            w1f[mt].w[0] = pkrne(we[0], we[1]);
            w1f[mt].w[1] = pkrne(we[2], we[3]);
            w1f[mt].w[2] = pkrne(we[4], we[5]);
            w1f[mt].w[3] = pkrne(we[6], we[7]);
        } else {
            w1f[mt].w[0] = pkrne(we[8], b1[row]);   // k=9 -> bias column
            w1f[mt].w[1] = 0; w1f[mt].w[2] = 0; w1f[mt].w[3] = 0;
        }
    }

    // ---- hidden-layer weight frags ----
    FragU wf[4][2][4];
    const float* wptr[4] = { w2, w3, w4, w5 };
#pragma unroll
    for (int L = 0; L < 4; ++L)
#pragma unroll
        for (int mt = 0; mt < 2; ++mt)
#pragma unroll
            for (int ks = 0; ks < 4; ++ks) {
                const float* src = wptr[L] + (32 * mt + m) * 64 + 16 * ks + 8 * lo;
                const float4 f0 = *(const float4*)(src);
                const float4 f1 = *(const float4*)(src + 4);
                wf[L][mt][ks].w[0] = pkrne(f0.x, f0.y);
                wf[L][mt][ks].w[1] = pkrne(f0.z, f0.w);
                wf[L][mt][ks].w[2] = pkrne(f1.x, f1.y);
                wf[L][mt][ks].w[3] = pkrne(f1.z, f1.w);
            }

    // ---- output-layer frags (rows 16..31 zero) ----
    FragU w6f[4];
    const bool vrow = (m < 16);
    const int r6 = vrow ? m : 0;
#pragma unroll
    for (int ks = 0; ks < 4; ++ks) {
        const float* src = w6 + r6 * 64 + 16 * ks + 8 * lo;
        const float4 f0 = *(const float4*)(src);
        const float4 f1 = *(const float4*)(src + 4);
        w6f[ks].w[0] = vrow ? pkrne(f0.x, f0.y) : 0;
        w6f[ks].w[1] = vrow ? pkrne(f0.z, f0.w) : 0;
        w6f[ks].w[2] = vrow ? pkrne(f1.x, f1.y) : 0;
        w6f[ks].w[3] = vrow ? pkrne(f1.z, f1.w) : 0;
    }

    // ---- pair loop: wave owns groups (2*pg, 2*pg+1) ----
    const int wid = (int)((blockIdx.x * blockDim.x + threadIdx.x) >> 6);
    const int nw  = (int)((gridDim.x * blockDim.x) >> 6);

    int pg = wid;
    float pa[9], pb[9];
    if (pg < NPAIR) {
        load_patches(x_in, 2 * pg + 0, m, pa);
        load_patches(x_in, 2 * pg + 1, m, pb);
    }

    const f32x16 z{};
    while (pg < NPAIR) {
        const int pgn = pg + nw;

        FragU B1a, B1b;
        pack_B1(pa, lo, B1a);
        pack_B1(pb, lo, B1b);

        // prefetch next pair's patches
        float na[9], nb[9];
        if (pgn < NPAIR) {
            load_patches(x_in, 2 * pgn + 0, m, na);
            load_patches(x_in, 2 * pgn + 1, m, nb);
        }

        // ---- layer 1 ----
        f32x16 aa0 = mfma16(w1f[0], B1a, z);
        f32x16 ab0 = mfma16(w1f[0], B1b, z);
        f32x16 aa1 = mfma16(w1f[1], B1a, z);
        f32x16 ab1 = mfma16(w1f[1], B1b, z);

        FragU Ba[4], Bb[4];
        epilogue<false>(aa0, aa1, Ba, nullptr);
        epilogue<false>(ab0, ab1, Bb, nullptr);

        // ---- layers 2..5 (both groups interleaved) ----
#pragma unroll
        for (int L = 0; L < 4; ++L) {
            f32x16 ca0 = z, ca1 = z, cb0 = z, cb1 = z;
#pragma unroll
            for (int ks = 0; ks < 4; ++ks) {
                ca0 = mfma16(wf[L][0][ks], Ba[ks], ca0);
                cb0 = mfma16(wf[L][0][ks], Bb[ks], cb0);
                ca1 = mfma16(wf[L][1][ks], Ba[ks], ca1);
                cb1 = mfma16(wf[L][1][ks], Bb[ks], cb1);
            }
            const u32* bb = bias_pk + L * 32 + lo * 16;
            epilogue<true>(ca0, ca1, Ba, bb);
            epilogue<true>(cb0, cb1, Bb, bb);
        }

        // ---- layer 6 ----
        f32x16 aFa = z, aFb = z;
#pragma unroll
        for (int ks = 0; ks < 4; ++ks) {
            aFa = mfma16(w6f[ks], Ba[ks], aFa);
            aFb = mfma16(w6f[ks], Bb[ks], aFb);
        }

        // ---- +b6, pixel-shuffle stores ----
#pragma unroll
        for (int gi = 0; gi < 2; ++gi) {
            const f32x16& aF = gi ? aFb : aFa;
            int cb, chp, cwp;
            calc_coords(2 * pg + gi, m, cb, chp, cwp);
            float* obase = out + (size_t)cb * (OW * OW) + (size_t)(4 * chp + lo) * OW + 4 * cwp;
            float4 v0 = make_float4(aF[0] + b6r[0], aF[1] + b6r[1],
                                    aF[2] + b6r[2], aF[3] + b6r[3]);
            float4 v1 = make_float4(aF[4] + b6r[4], aF[5] + b6r[5],
                                    aF[6] + b6r[6], aF[7] + b6r[7]);
            *(float4*)(obase)          = v0;   // row u1 = lo
            *(float4*)(obase + 2 * OW) = v1;   // row u1 = 2 + lo
        }

        pg = pgn;
#pragma unroll
        for (int k = 0; k < 9; ++k) { pa[k] = na[k]; pb[k] = nb[k]; }
    }
}

extern "C" void kernel_launch(void* const* d_in, const int* in_sizes, int n_in,
                              void* d_out, int out_size, void* d_ws, size_t ws_size,
                              hipStream_t stream)
{
    const float* x_in      = (const float*)d_in[0];
    const float* sampler_w = (const float*)d_in[1];
    // d_in[2] = sampler_b (reference multiplies it by 0 -> unused)
    const float* w1 = (const float*)d_in[3];
    const float* b1 = (const float*)d_in[4];
    const float* w2 = (const float*)d_in[5];
    const float* b2 = (const float*)d_in[6];
    const float* w3 = (const float*)d_in[7];
    const float* b3 = (const float*)d_in[8];
    const float* w4 = (const float*)d_in[9];
    const float* b4 = (const float*)d_in[10];
    const float* w5 = (const float*)d_in[11];
    const float* b5 = (const float*)d_in[12];
    const float* w6 = (const float*)d_in[13];
    const float* b6 = (const float*)d_in[14];
    float* out = (float*)d_out;

    dim3 grid(256);   // 1024 waves = 1 wave/SIMD co-resident
    dim3 block(256);
    hipLaunchKernelGGL(srnet_mfma, grid, block, 0, stream,
                       x_in, sampler_w, w1, b1, w2, b2, w3, b3,
                       w4, b4, w5, b5, w6, b6, out);
}